// Round 1
// 601.026 us; speedup vs baseline: 1.3454x; 1.3454x over previous
//
#include <hip/hip_runtime.h>
#include <stdint.h>

// Problem constants (from setup_inputs): E=8, T=2048, D=2048, I=1024
constexpr int E_ = 8, T_ = 2048, D_ = 2048, I_ = 1024;
#define EPS_ 1e-6f
#define QMAX_ 127.0f

typedef int v4i __attribute__((ext_vector_type(4)));
typedef uint32_t __attribute__((address_space(1))) u32g_t;
typedef uint32_t __attribute__((address_space(3))) u32l_t;

// Direct global->LDS DMA, 16B per lane. LDS dest is wave-uniform base + lane*16
// (m104); generic->AS3 truncation is the CK-standard addrspace cast.
__device__ __forceinline__ void load_lds16(const void* g, void* l) {
  __builtin_amdgcn_global_load_lds((u32g_t*)(uintptr_t)g, (u32l_t*)(uintptr_t)l,
                                   16, 0, 0);
}

// ---------------------------------------------------------------------------
// Stage-A column abs-max: partial[(e*16+rc)*cols + col] = max over RPC rows
// grid: (cols/256, 16, E), block 256
// ---------------------------------------------------------------------------
template <int RPC>
__global__ __launch_bounds__(256) void colmax_partial(
    const float* __restrict__ src, float* __restrict__ partial, int cols) {
  int e = blockIdx.z, rc = blockIdx.y;
  int col = blockIdx.x * 256 + threadIdx.x;
  const float* p = src + ((size_t)e * gridDim.y + rc) * RPC * cols + col;
  float m = 0.f;
#pragma unroll 8
  for (int r = 0; r < RPC; ++r) m = fmaxf(m, fabsf(p[(size_t)r * cols]));
  partial[((size_t)e * gridDim.y + rc) * cols + col] = m;
}

// ---------------------------------------------------------------------------
// s = max(sqrt(max(ax,EPS)/max(aw,EPS)), EPS), reducing 16 partials each
// grid: (cols/256, E)
// ---------------------------------------------------------------------------
__global__ __launch_bounds__(256) void compute_s(
    const float* __restrict__ px, const float* __restrict__ pw,
    float* __restrict__ s, int cols) {
  int e = blockIdx.y;
  int c = blockIdx.x * 256 + threadIdx.x;
  float ax = 0.f, aw = 0.f;
  for (int k = 0; k < 16; ++k) {
    ax = fmaxf(ax, px[((size_t)e * 16 + k) * cols + c]);
    aw = fmaxf(aw, pw[((size_t)e * 16 + k) * cols + c]);
  }
  float sv = sqrtf(fmaxf(ax, EPS_) / fmaxf(aw, EPS_));
  s[(size_t)e * cols + c] = fmaxf(sv, EPS_);
}

// ---------------------------------------------------------------------------
// Per-row quantize, wave-per-row (4 rows/block, shuffle-reduce max, no LDS).
// v = src*s (MUL) or src/s; scale = max(rowmax|v|,EPS)/127;
// q = clip(rint(v/scale),-127,127). grid (nrows/4, E), block 256.
// ---------------------------------------------------------------------------
template <bool MUL, int COLS>
__global__ __launch_bounds__(256) void quant_rows(
    const float* __restrict__ src, const float* __restrict__ s,
    int8_t* __restrict__ q, float* __restrict__ rscale, int nrows) {
  constexpr int NP = COLS / 256;  // float4 passes per lane (64 lanes * 4 floats)
  int e = blockIdx.y;
  int row = blockIdx.x * 4 + (threadIdx.x >> 6);
  int lane = threadIdx.x & 63;
  const float4* row4 = (const float4*)(src + ((size_t)e * nrows + row) * COLS);
  const float4* s4 = (const float4*)(s + (size_t)e * COLS);
  float4 vv[NP];
  float m = 0.f;
#pragma unroll
  for (int i = 0; i < NP; ++i) {
    int c = i * 64 + lane;
    float4 rv = row4[c], sv = s4[c];
    float4 v;
    v.x = MUL ? rv.x * sv.x : rv.x / sv.x;
    v.y = MUL ? rv.y * sv.y : rv.y / sv.y;
    v.z = MUL ? rv.z * sv.z : rv.z / sv.z;
    v.w = MUL ? rv.w * sv.w : rv.w / sv.w;
    vv[i] = v;
    m = fmaxf(m, fmaxf(fmaxf(fabsf(v.x), fabsf(v.y)), fmaxf(fabsf(v.z), fabsf(v.w))));
  }
#pragma unroll
  for (int off = 32; off > 0; off >>= 1) m = fmaxf(m, __shfl_xor(m, off, 64));
  float scale = fmaxf(m, EPS_) / QMAX_;
  char4* qrow = (char4*)(q + ((size_t)e * nrows + row) * COLS);
#pragma unroll
  for (int i = 0; i < NP; ++i) {
    int c = i * 64 + lane;
    float4 v = vv[i];
    char4 o;
    o.x = (int8_t)fminf(fmaxf(rintf(v.x / scale), -QMAX_), QMAX_);
    o.y = (int8_t)fminf(fmaxf(rintf(v.y / scale), -QMAX_), QMAX_);
    o.z = (int8_t)fminf(fmaxf(rintf(v.z / scale), -QMAX_), QMAX_);
    o.w = (int8_t)fminf(fmaxf(rintf(v.w / scale), -QMAX_), QMAX_);
    qrow[c] = o;
  }
  if (lane == 0) rscale[(size_t)e * nrows + row] = scale;
}

// ---------------------------------------------------------------------------
// int8 GEMM: C[m,n] = sum_k A[m,k]*B[n,k], dequant by asc[m]*bsc[n].
// BM=128, BN=64, BK=64, mfma_i32_16x16x64_i8 (one MFMA spans full BK).
// 2-phase double-buffered LDS via global_load_lds DMA (T3-minimum):
//   prologue stage buf0; loop { DMA next tile -> buf^1; ds_read+MFMA buf;
//   __syncthreads (vmcnt0+lgkm0+barrier); flip }  -- ONE barrier per K-step.
// LDS layout: linear 64B rows, content XOR-swizzled via the GLOBAL source
// address (rule #21): LDS(row,slot16)=G(row, slot^((row>>1)&3)); ds_read at
// slot = quad ^ ((l16>>1)&3) -> banks 2-way = free (m136).
// FUSE: gate+up tiles + SwiGLU epilogue + fused column-absmax partials of a.
// block 256 (4 waves 2x2), grid (NOUT/64, T/128, E).
// ---------------------------------------------------------------------------
template <bool FUSE, int K, int NOUT>
__global__ __launch_bounds__(256) void gemm_i8(
    const int8_t* __restrict__ Aq, const int8_t* __restrict__ Bq,
    const float* __restrict__ asc, const float* __restrict__ bsc,
    float* __restrict__ outp, float* __restrict__ pmax) {
  constexpr int BK = 64;
  constexpr int NK = K / BK;
  constexpr int NCH = FUSE ? 16 : 12;  // 1KB DMA chunks per K-step
  constexpr int CPW = NCH / 4;         // chunks per wave
  constexpr int TOT = 8192 + (FUSE ? 8192 : 4096);
  __shared__ int8_t lds[2][TOT];  // [buf][ A 8KB | B0 4KB | (B1 4KB) ]

  const int e = blockIdx.z;
  const int n0 = blockIdx.x * 64, m0 = blockIdx.y * 128;
  const int8_t* Ae = Aq + (size_t)e * T_ * K;
  const int8_t* Be = Bq + (size_t)e * 2048 * K;
  const int tid = threadIdx.x;
  const int lane = tid & 63, wv = tid >> 6;
  const int l16 = lane & 15, quad = lane >> 4;
  const int wm = wv & 1, wn = wv >> 1;
  const int lrow = lane >> 2;                               // row within chunk
  const int scol = ((lane & 3) ^ ((lane >> 3) & 3)) << 4;   // swizzled src slot
  const int swsel = ((quad ^ ((l16 >> 1) & 3)) << 4);       // swizzled read slot

  // Per-wave DMA chunk tables (chunk = 16 rows x 64B, lane i -> base+i*16)
  const int8_t* gsrc[CPW];
  int loff[CPW];
#pragma unroll
  for (int i = 0; i < CPW; ++i) {
    int c = wv * CPW + i;
    if (c < 8) {  // A rows [c*16, c*16+16)
      gsrc[i] = Ae + (size_t)(m0 + c * 16 + lrow) * K + scol;
      loff[i] = c * 1024;
    } else {  // B tile(s): cc 0..3 = gate/B0, cc 4..7 = up/B1
      int cc = c - 8;
      int br = n0 + ((FUSE && cc >= 4) ? I_ : 0) + (cc & 3) * 16 + lrow;
      gsrc[i] = Be + (size_t)br * K + scol;
      loff[i] = 8192 + cc * 1024;
    }
  }

  v4i accg[4][2], accu[4][2];
#pragma unroll
  for (int mt = 0; mt < 4; ++mt)
#pragma unroll
    for (int nt = 0; nt < 2; ++nt) {
      accg[mt][nt] = (v4i){0, 0, 0, 0};
      accu[mt][nt] = (v4i){0, 0, 0, 0};
    }

  // prologue: stage K-step 0 into buf 0
#pragma unroll
  for (int i = 0; i < CPW; ++i) load_lds16(gsrc[i], &lds[0][loff[i]]);
  __syncthreads();

  int cur = 0;
  for (int ks = 0; ks < NK; ++ks) {
    if (ks + 1 < NK) {  // prefetch next K-step (completes under this MFMA phase)
#pragma unroll
      for (int i = 0; i < CPW; ++i)
        load_lds16(gsrc[i] + (size_t)(ks + 1) * BK, &lds[cur ^ 1][loff[i]]);
    }
    const int8_t* La = &lds[cur][0];
    const int8_t* Lb = &lds[cur][8192];
    v4i af[4];
#pragma unroll
    for (int mt = 0; mt < 4; ++mt)
      af[mt] = *(const v4i*)(La + (wm * 64 + mt * 16 + l16) * 64 + swsel);
    v4i bf0[2], bf1[2];
#pragma unroll
    for (int nt = 0; nt < 2; ++nt) {
      int br = wn * 32 + nt * 16 + l16;
      bf0[nt] = *(const v4i*)(Lb + br * 64 + swsel);
      if (FUSE) bf1[nt] = *(const v4i*)(Lb + 4096 + br * 64 + swsel);
    }
#pragma unroll
    for (int mt = 0; mt < 4; ++mt)
#pragma unroll
      for (int nt = 0; nt < 2; ++nt) {
        accg[mt][nt] = __builtin_amdgcn_mfma_i32_16x16x64_i8(
            af[mt], bf0[nt], accg[mt][nt], 0, 0, 0);
        if (FUSE)
          accu[mt][nt] = __builtin_amdgcn_mfma_i32_16x16x64_i8(
              af[mt], bf1[nt], accu[mt][nt], 0, 0, 0);
      }
    __syncthreads();  // drains DMA (vmcnt0) + ds_reads (lgkm0) + barrier
    cur ^= 1;
  }

  const float* ascE = asc + (size_t)e * T_;
  const float* bscE = bsc + (size_t)e * 2048;
  float cml[2] = {0.f, 0.f};
#pragma unroll
  for (int mt = 0; mt < 4; ++mt)
#pragma unroll
    for (int nt = 0; nt < 2; ++nt)
#pragma unroll
      for (int r2 = 0; r2 < 4; ++r2) {
        int grow = m0 + wm * 64 + mt * 16 + quad * 4 + r2;
        int gcol = n0 + wn * 32 + nt * 16 + l16;
        float as = ascE[grow];
        if (FUSE) {
          float g = (float)accg[mt][nt][r2] * as * bscE[gcol];
          float u = (float)accu[mt][nt][r2] * as * bscE[I_ + gcol];
          float sg = g / (1.0f + expf(-g));  // silu
          float av = sg * u;
          outp[(size_t)e * T_ * NOUT + (size_t)grow * NOUT + gcol] = av;
          cml[nt] = fmaxf(cml[nt], fabsf(av));
        } else {
          outp[(size_t)e * T_ * NOUT + (size_t)grow * NOUT + gcol] =
              (float)accg[mt][nt][r2] * as * bscE[gcol];
        }
      }

  if (FUSE) {
    // Fused column-absmax of a over this block's 128 rows -> partial buffer
    // in exactly the colmax_partial layout: pmax[(e*16 + by)*NOUT + col].
    // float-bits atomicMax valid: all values >= 0.
    float* cmax = (float*)&lds[0][0];
    if (tid < 64) cmax[tid] = 0.f;
    __syncthreads();
#pragma unroll
    for (int nt = 0; nt < 2; ++nt)
      atomicMax((int*)&cmax[wn * 32 + nt * 16 + l16], __float_as_int(cml[nt]));
    __syncthreads();
    if (tid < 64)
      pmax[((size_t)e * 16 + blockIdx.y) * NOUT + n0 + tid] = cmax[tid];
  }
}

// ---------------------------------------------------------------------------
extern "C" void kernel_launch(void* const* d_in, const int* in_sizes, int n_in,
                              void* d_out, int out_size, void* d_ws, size_t ws_size,
                              hipStream_t stream) {
  const float* x   = (const float*)d_in[0];   // [E,T,D]
  const float* guw = (const float*)d_in[1];   // [E,2I,D]
  const float* dw  = (const float*)d_in[2];   // [E,D,I]
  float* out = (float*)d_out;                 // [E,T,D] fp32

  char* ws = (char*)d_ws;
  size_t off = 0;
  auto alloc = [&](size_t bytes) { char* p = ws + off; off += bytes; return p; };
  int8_t* xq   = (int8_t*)alloc((size_t)E_ * T_ * D_);        // 32 MB
  int8_t* wq1  = (int8_t*)alloc((size_t)E_ * 2 * I_ * D_);    // 32 MB
  int8_t* aq   = (int8_t*)alloc((size_t)E_ * T_ * I_);        // 16 MB
  int8_t* dwq  = (int8_t*)alloc((size_t)E_ * D_ * I_);        // 16 MB
  float*  a    = (float*)alloc((size_t)E_ * T_ * I_ * 4);     // 64 MB
  float*  px   = (float*)alloc((size_t)E_ * 16 * D_ * 4);
  float*  pw   = (float*)alloc((size_t)E_ * 16 * D_ * 4);
  float*  pdw  = (float*)alloc((size_t)E_ * 16 * I_ * 4);
  float*  pa   = (float*)alloc((size_t)E_ * 16 * I_ * 4);
  float*  s1   = (float*)alloc((size_t)E_ * D_ * 4);
  float*  s2   = (float*)alloc((size_t)E_ * I_ * 4);
  float*  xsc  = (float*)alloc((size_t)E_ * T_ * 4);
  float*  wsc1 = (float*)alloc((size_t)E_ * 2 * I_ * 4);
  float*  asc  = (float*)alloc((size_t)E_ * T_ * 4);
  float*  dwsc = (float*)alloc((size_t)E_ * D_ * 4);

  dim3 b(256);
  // Linear 1 smoothing scales
  colmax_partial<128><<<dim3(D_ / 256, 16, E_), b, 0, stream>>>(x, px, D_);
  colmax_partial<128><<<dim3(D_ / 256, 16, E_), b, 0, stream>>>(guw, pw, D_);
  colmax_partial<128><<<dim3(I_ / 256, 16, E_), b, 0, stream>>>(dw, pdw, I_);
  compute_s<<<dim3(D_ / 256, E_), b, 0, stream>>>(px, pw, s1, D_);
  // Quantize x (div by s) and guw (mul by s)
  quant_rows<false, D_><<<dim3(T_ / 4, E_), b, 0, stream>>>(x, s1, xq, xsc, T_);
  quant_rows<true, D_><<<dim3(2 * I_ / 4, E_), b, 0, stream>>>(guw, s1, wq1, wsc1, 2 * I_);
  // GEMM1 + SwiGLU -> a [E,T,I]; epilogue also emits colmax partials of a
  gemm_i8<true, D_, I_><<<dim3(I_ / 64, T_ / 128, E_), b, 0, stream>>>(
      xq, wq1, xsc, wsc1, a, pa);
  // Linear 2 smoothing scales (pa produced by GEMM1 epilogue)
  compute_s<<<dim3(I_ / 256, E_), b, 0, stream>>>(pa, pdw, s2, I_);
  quant_rows<false, I_><<<dim3(T_ / 4, E_), b, 0, stream>>>(a, s2, aq, asc, T_);
  quant_rows<true, I_><<<dim3(D_ / 4, E_), b, 0, stream>>>(dw, s2, dwq, dwsc, D_);
  // GEMM2 -> out [E,T,D]
  gemm_i8<false, I_, D_><<<dim3(D_ / 64, T_ / 128, E_), b, 0, stream>>>(
      aq, dwq, asc, dwsc, out, nullptr);
}